// Round 1
// baseline (930.497 us; speedup 1.0000x reference)
//
#include <hip/hip_runtime.h>
#include <math.h>

#define N_ 20000
#define E_ 320000
#define G_ 128
#define IN_ 16
#define H_ 64
#define L_ 4
#define C_ 10
#define AVG_D_LOG 2.8332133440562162f

union F4 { float4 v; float f[4]; };

// ---------------- preprocessing ----------------

__global__ __launch_bounds__(256) void k_zero(int* __restrict__ p, int n) {
  int i = blockIdx.x * 256 + threadIdx.x;
  if (i < n) p[i] = 0;
}

__global__ __launch_bounds__(256) void k_hist(const int* __restrict__ dst, int* __restrict__ deg) {
  int e = blockIdx.x * 256 + threadIdx.x;
  if (e < E_) atomicAdd(&deg[dst[e]], 1);
}

// single-block exclusive scan of deg -> offs, plus degree-derived scalers
__global__ __launch_bounds__(1024) void k_scan(const int* __restrict__ deg, int* __restrict__ offs,
    float* __restrict__ ampv, float* __restrict__ attv,
    float* __restrict__ invd, float* __restrict__ hnb) {
  __shared__ int sh[1024];
  int t = threadIdx.x;
  int base = t * 20;
  int local[20];
  int s = 0;
#pragma unroll
  for (int i = 0; i < 20; i++) {
    int idx = base + i;
    int v = (idx < N_) ? deg[idx] : 0;
    local[i] = s; s += v;
  }
  sh[t] = s;
  __syncthreads();
  for (int off = 1; off < 1024; off <<= 1) {
    int v = (t >= off) ? sh[t - off] : 0;
    __syncthreads();
    sh[t] += v;
    __syncthreads();
  }
  int excl = sh[t] - s;
#pragma unroll
  for (int i = 0; i < 20; i++) {
    int idx = base + i;
    if (idx < N_) offs[idx] = excl + local[i];
  }
  if (t == 0) offs[N_] = sh[1023];
  for (int idx = t; idx < N_; idx += 1024) {
    float d = (float)deg[idx];
    float logd = logf(d + 1.f);
    ampv[idx] = logd / AVG_D_LOG;
    attv[idx] = AVG_D_LOG / fmaxf(logd, 1e-5f);
    invd[idx] = 1.f / fmaxf(d, 1.f);
    hnb[idx] = d > 0.f ? 1.f : 0.f;
  }
}

__global__ __launch_bounds__(256) void k_scatter(const int* __restrict__ src, const int* __restrict__ dst,
    const int* __restrict__ offs, int* __restrict__ cursor, int* __restrict__ csr) {
  int e = blockIdx.x * 256 + threadIdx.x;
  if (e < E_) {
    int d = dst[e];
    int pos = offs[d] + atomicAdd(&cursor[d], 1);
    csr[pos] = src[e];
  }
}

// ---------------- embedding ----------------

__global__ __launch_bounds__(256) void k_embed(const float* __restrict__ h, const float* __restrict__ embW,
    const float* __restrict__ embB, float* __restrict__ x) {
  int n = blockIdx.x * 4 + (threadIdx.x >> 6);
  int c = threadIdx.x & 63;
  float acc = embB[c];
#pragma unroll
  for (int k = 0; k < IN_; k++) acc += h[n * IN_ + k] * embW[k * H_ + c];
  x[n * H_ + c] = acc;
}

// ---------------- pretrans: a = x@W_top, b = x@W_bot + bias ----------------

__global__ __launch_bounds__(256) void k_pretrans(const float* __restrict__ x, const float* __restrict__ W,
    const float* __restrict__ Bv, float* __restrict__ a, float* __restrict__ b) {
  __shared__ float xs[16 * 68];  // padded stride 68 to break bank aliasing
  int n0 = blockIdx.x * 16;
  int tid = threadIdx.x;
  for (int t = tid; t < 16 * 64; t += 256) xs[(t >> 6) * 68 + (t & 63)] = x[n0 * 64 + t];
  __syncthreads();
  int nl = tid >> 4, cq = tid & 15, c4 = cq * 4;
  F4 accA, accB;
  accA.v = make_float4(0.f, 0.f, 0.f, 0.f);
  accB.v = *(const float4*)(Bv + c4);
  const float* xp = xs + nl * 68;
#pragma unroll 2
  for (int k = 0; k < 64; k += 4) {
    F4 xv; xv.v = *(const float4*)(xp + k);
#pragma unroll
    for (int kk = 0; kk < 4; kk++) {
      float m = xv.f[kk];
      F4 wa, wb;
      wa.v = *(const float4*)(W + (k + kk) * 64 + c4);
      wb.v = *(const float4*)(W + (64 + k + kk) * 64 + c4);
#pragma unroll
      for (int i = 0; i < 4; i++) {
        accA.f[i] += m * wa.f[i];
        accB.f[i] += m * wb.f[i];
      }
    }
  }
  int n = n0 + nl;
  *(float4*)(a + n * 64 + c4) = accA.v;
  *(float4*)(b + n * 64 + c4) = accB.v;
}

// ---------------- aggregation: wave per node, 4 edges in flight ----------------

__global__ __launch_bounds__(256) void k_agg(const float* __restrict__ a, const float* __restrict__ b,
    const int* __restrict__ offs, const int* __restrict__ csr,
    const float* __restrict__ invd, const float* __restrict__ hnb, float* __restrict__ agg) {
  int lane = threadIdx.x & 63;
  int n = (blockIdx.x * 256 + threadIdx.x) >> 6;
  int q = lane & 15;    // channel quad: channels 4q..4q+3
  int eg = lane >> 4;   // edge group 0..3
  int o0 = offs[n];
  int deg = offs[n + 1] - o0;
  F4 bv; bv.v = *(const float4*)(b + n * 64 + q * 4);
  F4 sum, sq, mx, mn;
#pragma unroll
  for (int i = 0; i < 4; i++) {
    sum.f[i] = 0.f; sq.f[i] = 0.f;
    mx.f[i] = -__builtin_inff(); mn.f[i] = __builtin_inff();
  }
  for (int j = eg; j < deg; j += 4) {
    int s = csr[o0 + j];
    F4 av; av.v = *(const float4*)(a + s * 64 + q * 4);
#pragma unroll
    for (int i = 0; i < 4; i++) {
      float m = av.f[i] + bv.f[i];
      sum.f[i] += m;
      sq.f[i] += m * m;
      mx.f[i] = fmaxf(mx.f[i], m);
      mn.f[i] = fminf(mn.f[i], m);
    }
  }
  // combine the 4 edge groups (lanes differing in bits 4,5)
#pragma unroll
  for (int off = 16; off < 64; off <<= 1) {
#pragma unroll
    for (int i = 0; i < 4; i++) {
      sum.f[i] += __shfl_xor(sum.f[i], off);
      sq.f[i]  += __shfl_xor(sq.f[i], off);
      mx.f[i]  = fmaxf(mx.f[i], __shfl_xor(mx.f[i], off));
      mn.f[i]  = fminf(mn.f[i], __shfl_xor(mn.f[i], off));
    }
  }
  if (eg == 0) {
    float inv = invd[n], hn = hnb[n];
    F4 mean, stdv, mxo, mno;
#pragma unroll
    for (int i = 0; i < 4; i++) {
      mean.f[i] = sum.f[i] * inv;
      float var = sq.f[i] * inv - mean.f[i] * mean.f[i];
      stdv.f[i] = sqrtf(fmaxf(var, 0.f) + 1e-5f);
      mxo.f[i] = (hn > 0.5f) ? mx.f[i] : 0.f;
      mno.f[i] = (hn > 0.5f) ? mn.f[i] : 0.f;
    }
    *(float4*)(agg + n * 256 + q * 4) = mean.v;
    *(float4*)(agg + n * 256 + 64 + q * 4) = mxo.v;
    *(float4*)(agg + n * 256 + 128 + q * 4) = mno.v;
    *(float4*)(agg + n * 256 + 192 + q * 4) = stdv.v;
  }
}

// ---------------- posttrans + mix + graphnorm + residual (fused) ----------------

__global__ __launch_bounds__(256) void k_post(
    const float* __restrict__ agg, const float* __restrict__ W, const float* __restrict__ Bv,
    const float* __restrict__ mixW, const float* __restrict__ mixB,
    const float* __restrict__ ampv, const float* __restrict__ attv,
    const float* __restrict__ snorm, float* __restrict__ x) {
  __shared__ float aggs[16 * 260];  // stride 260: +4 bank offset per node
  __shared__ float xs[16 * 68];
  __shared__ float ys[16 * 68];
  int tid = threadIdx.x;
  int n0 = blockIdx.x * 16;
  for (int t = tid; t < 16 * 256; t += 256) aggs[(t >> 8) * 260 + (t & 255)] = agg[n0 * 256 + t];
  for (int t = tid; t < 16 * 64; t += 256) xs[(t >> 6) * 68 + (t & 63)] = x[n0 * 64 + t];
  __syncthreads();
  int nl = tid >> 4, cq = tid & 15, c4 = cq * 4;
  int n = n0 + nl;
  float ampn = ampv[n], attn = attv[n];
  F4 u; u.v = *(const float4*)(Bv + c4);
  const float* ap = aggs + nl * 260;
  // phase 1: identity scaler, W rows 0..255
#pragma unroll 2
  for (int k = 0; k < 256; k += 4) {
    F4 av; av.v = *(const float4*)(ap + k);
#pragma unroll
    for (int kk = 0; kk < 4; kk++) {
      F4 w; w.v = *(const float4*)(W + (k + kk) * 64 + c4);
      float m = av.f[kk];
#pragma unroll
      for (int i = 0; i < 4; i++) u.f[i] += m * w.f[i];
    }
  }
  // phase 2: amplification scaler, rows 256..511
#pragma unroll 2
  for (int k = 0; k < 256; k += 4) {
    F4 av; av.v = *(const float4*)(ap + k);
#pragma unroll
    for (int kk = 0; kk < 4; kk++) {
      F4 w; w.v = *(const float4*)(W + (256 + k + kk) * 64 + c4);
      float m = av.f[kk] * ampn;
#pragma unroll
      for (int i = 0; i < 4; i++) u.f[i] += m * w.f[i];
    }
  }
  // phase 3: attenuation scaler, rows 512..767
#pragma unroll 2
  for (int k = 0; k < 256; k += 4) {
    F4 av; av.v = *(const float4*)(ap + k);
#pragma unroll
    for (int kk = 0; kk < 4; kk++) {
      F4 w; w.v = *(const float4*)(W + (512 + k + kk) * 64 + c4);
      float m = av.f[kk] * attn;
#pragma unroll
      for (int i = 0; i < 4; i++) u.f[i] += m * w.f[i];
    }
  }
  // phase 4: x part, rows 768..831
  const float* xp = xs + nl * 68;
#pragma unroll 2
  for (int k = 0; k < 64; k += 4) {
    F4 xv; xv.v = *(const float4*)(xp + k);
#pragma unroll
    for (int kk = 0; kk < 4; kk++) {
      F4 w; w.v = *(const float4*)(W + (768 + k + kk) * 64 + c4);
      float m = xv.f[kk];
#pragma unroll
      for (int i = 0; i < 4; i++) u.f[i] += m * w.f[i];
    }
  }
  *(float4*)(ys + nl * 68 + c4) = u.v;
  __syncthreads();
  // mix: t = leaky_relu(y @ mixW + mixB); x = x_in + t * snorm
  F4 acc; acc.v = *(const float4*)(mixB + c4);
  const float* yp = ys + nl * 68;
#pragma unroll 2
  for (int k = 0; k < 64; k += 4) {
    F4 yv; yv.v = *(const float4*)(yp + k);
#pragma unroll
    for (int kk = 0; kk < 4; kk++) {
      F4 w; w.v = *(const float4*)(mixW + (k + kk) * 64 + c4);
      float m = yv.f[kk];
#pragma unroll
      for (int i = 0; i < 4; i++) acc.f[i] += m * w.f[i];
    }
  }
  float sn = snorm[n];
  F4 xv; xv.v = *(const float4*)(xp + c4);
  F4 outv;
#pragma unroll
  for (int i = 0; i < 4; i++) {
    float t2 = acc.f[i];
    t2 = t2 > 0.f ? t2 : 0.01f * t2;
    outv.f[i] = xv.f[i] + t2 * sn;
  }
  *(float4*)(x + n * 64 + c4) = outv.v;
}

// ---------------- readout ----------------

__global__ __launch_bounds__(256) void k_gsum(const float* __restrict__ x, const int* __restrict__ gid,
    float* __restrict__ gsum, float* __restrict__ gcnt) {
  int n = blockIdx.x * 4 + (threadIdx.x >> 6);
  int c = threadIdx.x & 63;
  int g = gid[n];
  atomicAdd(&gsum[g * 64 + c], x[n * 64 + c]);
  if (c == 0) atomicAdd(&gcnt[g], 1.f);
}

__global__ __launch_bounds__(64) void k_readout(const float* __restrict__ gs, const float* __restrict__ gc,
    const float* __restrict__ r1W, const float* __restrict__ r1B,
    const float* __restrict__ r2W, const float* __restrict__ r2B,
    const float* __restrict__ r3W, const float* __restrict__ r3B, float* __restrict__ out) {
  __shared__ float hg[64];
  __shared__ float t1[32];
  __shared__ float t2[16];
  int g = blockIdx.x, t = threadIdx.x;
  float cnt = fmaxf(gc[g], 1.f);
  hg[t] = gs[g * 64 + t] / cnt;
  __syncthreads();
  if (t < 32) {
    float acc = r1B[t];
#pragma unroll 8
    for (int k = 0; k < 64; k++) acc += hg[k] * r1W[k * 32 + t];
    t1[t] = fmaxf(acc, 0.f);
  }
  __syncthreads();
  if (t < 16) {
    float acc = r2B[t];
#pragma unroll 8
    for (int k = 0; k < 32; k++) acc += t1[k] * r2W[k * 16 + t];
    t2[t] = fmaxf(acc, 0.f);
  }
  __syncthreads();
  if (t < 10) {
    float acc = r3B[t];
#pragma unroll
    for (int k = 0; k < 16; k++) acc += t2[k] * r3W[k * 10 + t];
    out[g * 10 + t] = acc;
  }
}

// ---------------- launch ----------------

extern "C" void kernel_launch(void* const* d_in, const int* in_sizes, int n_in,
                              void* d_out, int out_size, void* d_ws, size_t ws_size,
                              hipStream_t stream) {
  const float* h     = (const float*)d_in[0];
  const float* snorm = (const float*)d_in[1];
  const float* embW  = (const float*)d_in[2];
  const float* embB  = (const float*)d_in[3];
  const float* preW  = (const float*)d_in[4];
  const float* preB  = (const float*)d_in[5];
  const float* postW = (const float*)d_in[6];
  const float* postB = (const float*)d_in[7];
  const float* mixW  = (const float*)d_in[8];
  const float* mixB  = (const float*)d_in[9];
  const float* r1W   = (const float*)d_in[10];
  const float* r1B   = (const float*)d_in[11];
  const float* r2W   = (const float*)d_in[12];
  const float* r2B   = (const float*)d_in[13];
  const float* r3W   = (const float*)d_in[14];
  const float* r3B   = (const float*)d_in[15];
  const int* src     = (const int*)d_in[16];
  const int* dst     = (const int*)d_in[17];
  const int* gid     = (const int*)d_in[18];
  float* out = (float*)d_out;

  char* w = (char*)d_ws;
  float* x    = (float*)w; w += (size_t)N_ * 64 * 4;
  float* av   = (float*)w; w += (size_t)N_ * 64 * 4;
  float* bv   = (float*)w; w += (size_t)N_ * 64 * 4;
  float* agg  = (float*)w; w += (size_t)N_ * 256 * 4;
  float* ampv = (float*)w; w += (size_t)N_ * 4;
  float* attv = (float*)w; w += (size_t)N_ * 4;
  float* invd = (float*)w; w += (size_t)N_ * 4;
  float* hnb  = (float*)w; w += (size_t)N_ * 4;
  int* csr    = (int*)w;   w += (size_t)E_ * 4;
  int* offs   = (int*)w;   w += (size_t)(N_ + 64) * 4;
  int* zbase  = (int*)w;
  int* deg    = (int*)w;   w += (size_t)N_ * 4;
  int* cursor = (int*)w;   w += (size_t)N_ * 4;
  float* gsum = (float*)w; w += (size_t)G_ * 64 * 4;
  float* gcnt = (float*)w; w += 128 * 4;
  int zcount = N_ + N_ + G_ * 64 + 128;

  k_zero<<<(zcount + 255) / 256, 256, 0, stream>>>(zbase, zcount);
  k_hist<<<E_ / 256, 256, 0, stream>>>(dst, deg);
  k_scan<<<1, 1024, 0, stream>>>(deg, offs, ampv, attv, invd, hnb);
  k_scatter<<<E_ / 256, 256, 0, stream>>>(src, dst, offs, cursor, csr);
  k_embed<<<N_ / 4, 256, 0, stream>>>(h, embW, embB, x);
  for (int l = 0; l < L_; l++) {
    k_pretrans<<<N_ / 16, 256, 0, stream>>>(x, preW + l * 2 * H_ * H_, preB + l * H_, av, bv);
    k_agg<<<N_ / 4, 256, 0, stream>>>(av, bv, offs, csr, invd, hnb, agg);
    k_post<<<N_ / 16, 256, 0, stream>>>(agg, postW + l * 13 * H_ * H_, postB + l * H_,
                                        mixW + l * H_ * H_, mixB + l * H_, ampv, attv, snorm, x);
  }
  k_gsum<<<N_ / 4, 256, 0, stream>>>(x, gid, gsum, gcnt);
  k_readout<<<G_, 64, 0, stream>>>(gsum, gcnt, r1W, r1B, r2W, r2B, r3W, r3B, out);
}

// Round 2
// 606.094 us; speedup vs baseline: 1.5352x; 1.5352x over previous
//
#include <hip/hip_runtime.h>
#include <math.h>

#define N_ 20000
#define E_ 320000
#define G_ 128
#define IN_ 16
#define H_ 64
#define L_ 4
#define C_ 10
#define AVG_D_LOG 2.8332133440562162f

union F4 { float4 v; float f[4]; };

// ---------------- preprocessing ----------------

__global__ __launch_bounds__(256) void k_zero(int* __restrict__ p, int n) {
  int i = blockIdx.x * 256 + threadIdx.x;
  if (i < n) p[i] = 0;
}

__global__ __launch_bounds__(256) void k_hist(const int* __restrict__ dst, int* __restrict__ deg) {
  int e = blockIdx.x * 256 + threadIdx.x;
  if (e < E_) atomicAdd(&deg[dst[e]], 1);
}

// single-block exclusive scan of deg -> offs, plus degree-derived scalers
__global__ __launch_bounds__(1024) void k_scan(const int* __restrict__ deg, int* __restrict__ offs,
    float* __restrict__ ampv, float* __restrict__ attv,
    float* __restrict__ invd, float* __restrict__ hnb) {
  __shared__ int sh[1024];
  int t = threadIdx.x;
  int base = t * 20;
  int local[20];
  int s = 0;
#pragma unroll
  for (int i = 0; i < 20; i++) {
    int idx = base + i;
    int v = (idx < N_) ? deg[idx] : 0;
    local[i] = s; s += v;
  }
  sh[t] = s;
  __syncthreads();
  for (int off = 1; off < 1024; off <<= 1) {
    int v = (t >= off) ? sh[t - off] : 0;
    __syncthreads();
    sh[t] += v;
    __syncthreads();
  }
  int excl = sh[t] - s;
#pragma unroll
  for (int i = 0; i < 20; i++) {
    int idx = base + i;
    if (idx < N_) offs[idx] = excl + local[i];
  }
  if (t == 0) offs[N_] = sh[1023];
  for (int idx = t; idx < N_; idx += 1024) {
    float d = (float)deg[idx];
    float logd = logf(d + 1.f);
    ampv[idx] = logd / AVG_D_LOG;
    attv[idx] = AVG_D_LOG / fmaxf(logd, 1e-5f);
    invd[idx] = 1.f / fmaxf(d, 1.f);
    hnb[idx] = d > 0.f ? 1.f : 0.f;
  }
}

__global__ __launch_bounds__(256) void k_scatter(const int* __restrict__ src, const int* __restrict__ dst,
    const int* __restrict__ offs, int* __restrict__ cursor, int* __restrict__ csr) {
  int e = blockIdx.x * 256 + threadIdx.x;
  if (e < E_) {
    int d = dst[e];
    int pos = offs[d] + atomicAdd(&cursor[d], 1);
    csr[pos] = src[e];
  }
}

// ---------------- embedding ----------------

__global__ __launch_bounds__(256) void k_embed(const float* __restrict__ h, const float* __restrict__ embW,
    const float* __restrict__ embB, float* __restrict__ x) {
  int n = blockIdx.x * 4 + (threadIdx.x >> 6);
  int c = threadIdx.x & 63;
  float acc = embB[c];
#pragma unroll
  for (int k = 0; k < IN_; k++) acc += h[n * IN_ + k] * embW[k * H_ + c];
  x[n * H_ + c] = acc;
}

// ---------------- pretrans: a = x@W_top, b = x@W_bot + bias ----------------
// 64 nodes/block; thread = (node-group of 4) x (channel quad). 16 FMA per W load.

__global__ __launch_bounds__(256) void k_pretrans(const float* __restrict__ x, const float* __restrict__ W,
    const float* __restrict__ Bv, float* __restrict__ a, float* __restrict__ b) {
  __shared__ float xs[64 * 68];
  int tid = threadIdx.x;
  int n0 = blockIdx.x * 64;
#pragma unroll
  for (int s = 0; s < 4; s++) {
    int fi = tid + s * 256;
    int node = fi >> 4, jj = (fi & 15) * 4;
    int ng_g = n0 + node; if (ng_g > N_ - 1) ng_g = N_ - 1;
    *(float4*)(xs + node * 68 + jj) = *(const float4*)(x + (size_t)ng_g * 64 + jj);
  }
  __syncthreads();
  int cq = tid & 15, ng = tid >> 4;
  int c4 = cq * 4;
  F4 accA[4], accB[4];
  F4 bias; bias.v = *(const float4*)(Bv + c4);
#pragma unroll
  for (int i = 0; i < 4; i++) {
    accA[i].v = make_float4(0.f, 0.f, 0.f, 0.f);
    accB[i].v = bias.v;
  }
#pragma unroll 2
  for (int k = 0; k < 64; k += 4) {
    F4 av[4];
#pragma unroll
    for (int i = 0; i < 4; i++) av[i].v = *(const float4*)(xs + (ng * 4 + i) * 68 + k);
#pragma unroll
    for (int kk = 0; kk < 4; kk++) {
      F4 wa, wb;
      wa.v = *(const float4*)(W + (k + kk) * 64 + c4);
      wb.v = *(const float4*)(W + (64 + k + kk) * 64 + c4);
#pragma unroll
      for (int i = 0; i < 4; i++) {
        float m = av[i].f[kk];
#pragma unroll
        for (int j = 0; j < 4; j++) {
          accA[i].f[j] += m * wa.f[j];
          accB[i].f[j] += m * wb.f[j];
        }
      }
    }
  }
#pragma unroll
  for (int i = 0; i < 4; i++) {
    int n = n0 + ng * 4 + i;
    if (n < N_) {
      *(float4*)(a + (size_t)n * 64 + c4) = accA[i].v;
      *(float4*)(b + (size_t)n * 64 + c4) = accB[i].v;
    }
  }
}

// ---------------- aggregation: wave per node, 4 edges in flight ----------------

__global__ __launch_bounds__(256) void k_agg(const float* __restrict__ a, const float* __restrict__ b,
    const int* __restrict__ offs, const int* __restrict__ csr,
    const float* __restrict__ invd, const float* __restrict__ hnb, float* __restrict__ agg) {
  int lane = threadIdx.x & 63;
  int n = (blockIdx.x * 256 + threadIdx.x) >> 6;
  int q = lane & 15;    // channel quad: channels 4q..4q+3
  int eg = lane >> 4;   // edge group 0..3
  int o0 = offs[n];
  int deg = offs[n + 1] - o0;
  F4 bv; bv.v = *(const float4*)(b + n * 64 + q * 4);
  F4 sum, sq, mx, mn;
#pragma unroll
  for (int i = 0; i < 4; i++) {
    sum.f[i] = 0.f; sq.f[i] = 0.f;
    mx.f[i] = -__builtin_inff(); mn.f[i] = __builtin_inff();
  }
  for (int j = eg; j < deg; j += 4) {
    int s = csr[o0 + j];
    F4 av; av.v = *(const float4*)(a + s * 64 + q * 4);
#pragma unroll
    for (int i = 0; i < 4; i++) {
      float m = av.f[i] + bv.f[i];
      sum.f[i] += m;
      sq.f[i] += m * m;
      mx.f[i] = fmaxf(mx.f[i], m);
      mn.f[i] = fminf(mn.f[i], m);
    }
  }
#pragma unroll
  for (int off = 16; off < 64; off <<= 1) {
#pragma unroll
    for (int i = 0; i < 4; i++) {
      sum.f[i] += __shfl_xor(sum.f[i], off);
      sq.f[i]  += __shfl_xor(sq.f[i], off);
      mx.f[i]  = fmaxf(mx.f[i], __shfl_xor(mx.f[i], off));
      mn.f[i]  = fminf(mn.f[i], __shfl_xor(mn.f[i], off));
    }
  }
  if (eg == 0) {
    float inv = invd[n], hn = hnb[n];
    F4 mean, stdv, mxo, mno;
#pragma unroll
    for (int i = 0; i < 4; i++) {
      mean.f[i] = sum.f[i] * inv;
      float var = sq.f[i] * inv - mean.f[i] * mean.f[i];
      stdv.f[i] = sqrtf(fmaxf(var, 0.f) + 1e-5f);
      mxo.f[i] = (hn > 0.5f) ? mx.f[i] : 0.f;
      mno.f[i] = (hn > 0.5f) ? mn.f[i] : 0.f;
    }
    *(float4*)(agg + n * 256 + q * 4) = mean.v;
    *(float4*)(agg + n * 256 + 64 + q * 4) = mxo.v;
    *(float4*)(agg + n * 256 + 128 + q * 4) = mno.v;
    *(float4*)(agg + n * 256 + 192 + q * 4) = stdv.v;
  }
}

// ---------------- posttrans + mix + graphnorm + residual (fused) ----------------
// 64 nodes/block, thread = 4 nodes x 4 channels. Three accumulator sets
// (identity/amp/att) so agg is read ONCE; scalers applied in epilogue.

__global__ __launch_bounds__(256) void k_post(
    const float* __restrict__ agg, const float* __restrict__ W, const float* __restrict__ Bv,
    const float* __restrict__ mixW, const float* __restrict__ mixB,
    const float* __restrict__ ampv, const float* __restrict__ attv,
    const float* __restrict__ snorm, float* __restrict__ x) {
  __shared__ float atile[64 * 68];  // streamed agg k-chunk, later reused as y
  __shared__ float xs[64 * 68];
  __shared__ float ampL[64], attL[64], snL[64];
  int tid = threadIdx.x;
  int n0 = blockIdx.x * 64;
#pragma unroll
  for (int s = 0; s < 4; s++) {
    int fi = tid + s * 256;
    int node = fi >> 4, jj = (fi & 15) * 4;
    int ng_g = n0 + node; if (ng_g > N_ - 1) ng_g = N_ - 1;
    *(float4*)(xs + node * 68 + jj) = *(const float4*)(x + (size_t)ng_g * 64 + jj);
  }
  if (tid < 64) {
    int n = n0 + tid; if (n > N_ - 1) n = N_ - 1;
    ampL[tid] = ampv[n];
    attL[tid] = attv[n];
    snL[tid] = snorm[n];
  }
  int cq = tid & 15, ng = tid >> 4;
  int c4 = cq * 4;
  F4 uI[4], uA[4], uT[4];
#pragma unroll
  for (int i = 0; i < 4; i++) {
    uI[i].v = make_float4(0.f, 0.f, 0.f, 0.f);
    uA[i].v = make_float4(0.f, 0.f, 0.f, 0.f);
    uT[i].v = make_float4(0.f, 0.f, 0.f, 0.f);
  }
#pragma unroll 1
  for (int c = 0; c < 4; c++) {
    __syncthreads();
#pragma unroll
    for (int s = 0; s < 4; s++) {
      int fi = tid + s * 256;
      int node = fi >> 4, jj = (fi & 15) * 4;
      int ng_g = n0 + node; if (ng_g > N_ - 1) ng_g = N_ - 1;
      *(float4*)(atile + node * 68 + jj) =
          *(const float4*)(agg + (size_t)ng_g * 256 + c * 64 + jj);
    }
    __syncthreads();
    const float* W0 = W + (size_t)(c * 64) * 64;
    const float* W1 = W + (size_t)(256 + c * 64) * 64;
    const float* W2 = W + (size_t)(512 + c * 64) * 64;
#pragma unroll 2
    for (int k = 0; k < 64; k += 4) {
      F4 av[4];
#pragma unroll
      for (int i = 0; i < 4; i++) av[i].v = *(const float4*)(atile + (ng * 4 + i) * 68 + k);
#pragma unroll
      for (int kk = 0; kk < 4; kk++) {
        F4 w0, w1, w2;
        w0.v = *(const float4*)(W0 + (k + kk) * 64 + c4);
        w1.v = *(const float4*)(W1 + (k + kk) * 64 + c4);
        w2.v = *(const float4*)(W2 + (k + kk) * 64 + c4);
#pragma unroll
        for (int i = 0; i < 4; i++) {
          float m = av[i].f[kk];
#pragma unroll
          for (int j = 0; j < 4; j++) {
            uI[i].f[j] += m * w0.f[j];
            uA[i].f[j] += m * w1.f[j];
            uT[i].f[j] += m * w2.f[j];
          }
        }
      }
    }
  }
  // x part: rows 768..831 (into identity accumulator)
  {
    const float* W3 = W + (size_t)768 * 64;
#pragma unroll 2
    for (int k = 0; k < 64; k += 4) {
      F4 av[4];
#pragma unroll
      for (int i = 0; i < 4; i++) av[i].v = *(const float4*)(xs + (ng * 4 + i) * 68 + k);
#pragma unroll
      for (int kk = 0; kk < 4; kk++) {
        F4 w; w.v = *(const float4*)(W3 + (k + kk) * 64 + c4);
#pragma unroll
        for (int i = 0; i < 4; i++) {
          float m = av[i].f[kk];
#pragma unroll
          for (int j = 0; j < 4; j++) uI[i].f[j] += m * w.f[j];
        }
      }
    }
  }
  // combine scalers + bias -> y staged into atile
  __syncthreads();
  {
    F4 bias; bias.v = *(const float4*)(Bv + c4);
#pragma unroll
    for (int i = 0; i < 4; i++) {
      float amp = ampL[ng * 4 + i], att = attL[ng * 4 + i];
      F4 y;
#pragma unroll
      for (int j = 0; j < 4; j++)
        y.f[j] = uI[i].f[j] + bias.f[j] + amp * uA[i].f[j] + att * uT[i].f[j];
      *(float4*)(atile + (ng * 4 + i) * 68 + c4) = y.v;
    }
  }
  __syncthreads();
  // mix: t = leaky_relu(y @ mixW + mixB); x = x_in + t * snorm
  F4 acc[4];
  {
    F4 mb; mb.v = *(const float4*)(mixB + c4);
#pragma unroll
    for (int i = 0; i < 4; i++) acc[i].v = mb.v;
  }
#pragma unroll 2
  for (int k = 0; k < 64; k += 4) {
    F4 av[4];
#pragma unroll
    for (int i = 0; i < 4; i++) av[i].v = *(const float4*)(atile + (ng * 4 + i) * 68 + k);
#pragma unroll
    for (int kk = 0; kk < 4; kk++) {
      F4 w; w.v = *(const float4*)(mixW + (k + kk) * 64 + c4);
#pragma unroll
      for (int i = 0; i < 4; i++) {
        float m = av[i].f[kk];
#pragma unroll
        for (int j = 0; j < 4; j++) acc[i].f[j] += m * w.f[j];
      }
    }
  }
#pragma unroll
  for (int i = 0; i < 4; i++) {
    int n = n0 + ng * 4 + i;
    if (n < N_) {
      float sn = snL[ng * 4 + i];
      F4 xv; xv.v = *(const float4*)(xs + (ng * 4 + i) * 68 + c4);
      F4 outv;
#pragma unroll
      for (int j = 0; j < 4; j++) {
        float t2 = acc[i].f[j];
        t2 = t2 > 0.f ? t2 : 0.01f * t2;
        outv.f[j] = xv.f[j] + t2 * sn;
      }
      *(float4*)(x + (size_t)n * 64 + c4) = outv.v;
    }
  }
}

// ---------------- readout ----------------

__global__ __launch_bounds__(256) void k_gsum(const float* __restrict__ x, const int* __restrict__ gid,
    float* __restrict__ gsum, float* __restrict__ gcnt) {
  int n = blockIdx.x * 4 + (threadIdx.x >> 6);
  int c = threadIdx.x & 63;
  int g = gid[n];
  atomicAdd(&gsum[g * 64 + c], x[n * 64 + c]);
  if (c == 0) atomicAdd(&gcnt[g], 1.f);
}

__global__ __launch_bounds__(64) void k_readout(const float* __restrict__ gs, const float* __restrict__ gc,
    const float* __restrict__ r1W, const float* __restrict__ r1B,
    const float* __restrict__ r2W, const float* __restrict__ r2B,
    const float* __restrict__ r3W, const float* __restrict__ r3B, float* __restrict__ out) {
  __shared__ float hg[64];
  __shared__ float t1[32];
  __shared__ float t2[16];
  int g = blockIdx.x, t = threadIdx.x;
  float cnt = fmaxf(gc[g], 1.f);
  hg[t] = gs[g * 64 + t] / cnt;
  __syncthreads();
  if (t < 32) {
    float acc = r1B[t];
#pragma unroll 8
    for (int k = 0; k < 64; k++) acc += hg[k] * r1W[k * 32 + t];
    t1[t] = fmaxf(acc, 0.f);
  }
  __syncthreads();
  if (t < 16) {
    float acc = r2B[t];
#pragma unroll 8
    for (int k = 0; k < 32; k++) acc += t1[k] * r2W[k * 16 + t];
    t2[t] = fmaxf(acc, 0.f);
  }
  __syncthreads();
  if (t < 10) {
    float acc = r3B[t];
#pragma unroll
    for (int k = 0; k < 16; k++) acc += t2[k] * r3W[k * 10 + t];
    out[g * 10 + t] = acc;
  }
}

// ---------------- launch ----------------

extern "C" void kernel_launch(void* const* d_in, const int* in_sizes, int n_in,
                              void* d_out, int out_size, void* d_ws, size_t ws_size,
                              hipStream_t stream) {
  const float* h     = (const float*)d_in[0];
  const float* snorm = (const float*)d_in[1];
  const float* embW  = (const float*)d_in[2];
  const float* embB  = (const float*)d_in[3];
  const float* preW  = (const float*)d_in[4];
  const float* preB  = (const float*)d_in[5];
  const float* postW = (const float*)d_in[6];
  const float* postB = (const float*)d_in[7];
  const float* mixW  = (const float*)d_in[8];
  const float* mixB  = (const float*)d_in[9];
  const float* r1W   = (const float*)d_in[10];
  const float* r1B   = (const float*)d_in[11];
  const float* r2W   = (const float*)d_in[12];
  const float* r2B   = (const float*)d_in[13];
  const float* r3W   = (const float*)d_in[14];
  const float* r3B   = (const float*)d_in[15];
  const int* src     = (const int*)d_in[16];
  const int* dst     = (const int*)d_in[17];
  const int* gid     = (const int*)d_in[18];
  float* out = (float*)d_out;

  char* w = (char*)d_ws;
  float* x    = (float*)w; w += (size_t)N_ * 64 * 4;
  float* av   = (float*)w; w += (size_t)N_ * 64 * 4;
  float* bv   = (float*)w; w += (size_t)N_ * 64 * 4;
  float* agg  = (float*)w; w += (size_t)N_ * 256 * 4;
  float* ampv = (float*)w; w += (size_t)N_ * 4;
  float* attv = (float*)w; w += (size_t)N_ * 4;
  float* invd = (float*)w; w += (size_t)N_ * 4;
  float* hnb  = (float*)w; w += (size_t)N_ * 4;
  int* csr    = (int*)w;   w += (size_t)E_ * 4;
  int* offs   = (int*)w;   w += (size_t)(N_ + 64) * 4;
  int* zbase  = (int*)w;
  int* deg    = (int*)w;   w += (size_t)N_ * 4;
  int* cursor = (int*)w;   w += (size_t)N_ * 4;
  float* gsum = (float*)w; w += (size_t)G_ * 64 * 4;
  float* gcnt = (float*)w; w += 128 * 4;
  int zcount = N_ + N_ + G_ * 64 + 128;

  k_zero<<<(zcount + 255) / 256, 256, 0, stream>>>(zbase, zcount);
  k_hist<<<E_ / 256, 256, 0, stream>>>(dst, deg);
  k_scan<<<1, 1024, 0, stream>>>(deg, offs, ampv, attv, invd, hnb);
  k_scatter<<<E_ / 256, 256, 0, stream>>>(src, dst, offs, cursor, csr);
  k_embed<<<N_ / 4, 256, 0, stream>>>(h, embW, embB, x);
  for (int l = 0; l < L_; l++) {
    k_pretrans<<<(N_ + 63) / 64, 256, 0, stream>>>(x, preW + l * 2 * H_ * H_, preB + l * H_, av, bv);
    k_agg<<<N_ / 4, 256, 0, stream>>>(av, bv, offs, csr, invd, hnb, agg);
    k_post<<<(N_ + 63) / 64, 256, 0, stream>>>(agg, postW + l * 13 * H_ * H_, postB + l * H_,
                                               mixW + l * H_ * H_, mixB + l * H_, ampv, attv, snorm, x);
  }
  k_gsum<<<N_ / 4, 256, 0, stream>>>(x, gid, gsum, gcnt);
  k_readout<<<G_, 64, 0, stream>>>(gsum, gcnt, r1W, r1B, r2W, r2B, r3W, r3B, out);
}

// Round 3
// 544.224 us; speedup vs baseline: 1.7098x; 1.1137x over previous
//
#include <hip/hip_runtime.h>
#include <math.h>

#define N_ 20000
#define E_ 320000
#define G_ 128
#define IN_ 16
#define H_ 64
#define L_ 4
#define C_ 10
#define AVG_D_LOG 2.8332133440562162f

union F4 { float4 v; float f[4]; };

// ---------------- preprocessing ----------------

__global__ __launch_bounds__(256) void k_zero(int* __restrict__ p, int n) {
  int i = blockIdx.x * 256 + threadIdx.x;
  if (i < n) p[i] = 0;
}

__global__ __launch_bounds__(256) void k_hist(const int* __restrict__ dst, int* __restrict__ deg) {
  int e = blockIdx.x * 256 + threadIdx.x;
  if (e < E_) atomicAdd(&deg[dst[e]], 1);
}

// single-block exclusive scan of deg -> offs, plus degree-derived scalers
__global__ __launch_bounds__(1024) void k_scan(const int* __restrict__ deg, int* __restrict__ offs,
    float* __restrict__ ampv, float* __restrict__ attv,
    float* __restrict__ invd, float* __restrict__ hnb) {
  __shared__ int sh[1024];
  int t = threadIdx.x;
  int base = t * 20;
  int local[20];
  int s = 0;
#pragma unroll
  for (int i = 0; i < 20; i++) {
    int idx = base + i;
    int v = (idx < N_) ? deg[idx] : 0;
    local[i] = s; s += v;
  }
  sh[t] = s;
  __syncthreads();
  for (int off = 1; off < 1024; off <<= 1) {
    int v = (t >= off) ? sh[t - off] : 0;
    __syncthreads();
    sh[t] += v;
    __syncthreads();
  }
  int excl = sh[t] - s;
#pragma unroll
  for (int i = 0; i < 20; i++) {
    int idx = base + i;
    if (idx < N_) offs[idx] = excl + local[i];
  }
  if (t == 0) offs[N_] = sh[1023];
  for (int idx = t; idx < N_; idx += 1024) {
    float d = (float)deg[idx];
    float logd = logf(d + 1.f);
    ampv[idx] = logd / AVG_D_LOG;
    attv[idx] = AVG_D_LOG / fmaxf(logd, 1e-5f);
    invd[idx] = 1.f / fmaxf(d, 1.f);
    hnb[idx] = d > 0.f ? 1.f : 0.f;
  }
}

__global__ __launch_bounds__(256) void k_scatter(const int* __restrict__ src, const int* __restrict__ dst,
    const int* __restrict__ offs, int* __restrict__ cursor, int* __restrict__ csr) {
  int e = blockIdx.x * 256 + threadIdx.x;
  if (e < E_) {
    int d = dst[e];
    int pos = offs[d] + atomicAdd(&cursor[d], 1);
    csr[pos] = src[e];
  }
}

// ---------------- embedding ----------------

__global__ __launch_bounds__(256) void k_embed(const float* __restrict__ h, const float* __restrict__ embW,
    const float* __restrict__ embB, float* __restrict__ x) {
  int n = blockIdx.x * 4 + (threadIdx.x >> 6);
  int c = threadIdx.x & 63;
  float acc = embB[c];
#pragma unroll
  for (int k = 0; k < IN_; k++) acc += h[n * IN_ + k] * embW[k * H_ + c];
  x[n * H_ + c] = acc;
}

// ---------------- pretrans: a = x@W_top, b = x@W_bot + bias ----------------
// 64 nodes/block; thread = (node-group of 4) x (channel quad). 16 FMA per W load.

__global__ __launch_bounds__(256) void k_pretrans(const float* __restrict__ x, const float* __restrict__ W,
    const float* __restrict__ Bv, float* __restrict__ a, float* __restrict__ b) {
  __shared__ float xs[64 * 68];
  int tid = threadIdx.x;
  int n0 = blockIdx.x * 64;
#pragma unroll
  for (int s = 0; s < 4; s++) {
    int fi = tid + s * 256;
    int node = fi >> 4, jj = (fi & 15) * 4;
    int ng_g = n0 + node; if (ng_g > N_ - 1) ng_g = N_ - 1;
    *(float4*)(xs + node * 68 + jj) = *(const float4*)(x + (size_t)ng_g * 64 + jj);
  }
  __syncthreads();
  int cq = tid & 15, ng = tid >> 4;
  int c4 = cq * 4;
  F4 accA[4], accB[4];
  F4 bias; bias.v = *(const float4*)(Bv + c4);
#pragma unroll
  for (int i = 0; i < 4; i++) {
    accA[i].v = make_float4(0.f, 0.f, 0.f, 0.f);
    accB[i].v = bias.v;
  }
#pragma unroll 2
  for (int k = 0; k < 64; k += 4) {
    F4 av[4];
#pragma unroll
    for (int i = 0; i < 4; i++) av[i].v = *(const float4*)(xs + (ng * 4 + i) * 68 + k);
#pragma unroll
    for (int kk = 0; kk < 4; kk++) {
      F4 wa, wb;
      wa.v = *(const float4*)(W + (k + kk) * 64 + c4);
      wb.v = *(const float4*)(W + (64 + k + kk) * 64 + c4);
#pragma unroll
      for (int i = 0; i < 4; i++) {
        float m = av[i].f[kk];
#pragma unroll
        for (int j = 0; j < 4; j++) {
          accA[i].f[j] += m * wa.f[j];
          accB[i].f[j] += m * wb.f[j];
        }
      }
    }
  }
#pragma unroll
  for (int i = 0; i < 4; i++) {
    int n = n0 + ng * 4 + i;
    if (n < N_) {
      *(float4*)(a + (size_t)n * 64 + c4) = accA[i].v;
      *(float4*)(b + (size_t)n * 64 + c4) = accB[i].v;
    }
  }
}

// ---------------- aggregation: wave per node, 4 edges in flight ----------------

__global__ __launch_bounds__(256) void k_agg(const float* __restrict__ a, const float* __restrict__ b,
    const int* __restrict__ offs, const int* __restrict__ csr,
    const float* __restrict__ invd, const float* __restrict__ hnb, float* __restrict__ agg) {
  int lane = threadIdx.x & 63;
  int n = (blockIdx.x * 256 + threadIdx.x) >> 6;
  int q = lane & 15;    // channel quad: channels 4q..4q+3
  int eg = lane >> 4;   // edge group 0..3
  int o0 = offs[n];
  int deg = offs[n + 1] - o0;
  F4 bv; bv.v = *(const float4*)(b + n * 64 + q * 4);
  F4 sum, sq, mx, mn;
#pragma unroll
  for (int i = 0; i < 4; i++) {
    sum.f[i] = 0.f; sq.f[i] = 0.f;
    mx.f[i] = -__builtin_inff(); mn.f[i] = __builtin_inff();
  }
  for (int j = eg; j < deg; j += 4) {
    int s = csr[o0 + j];
    F4 av; av.v = *(const float4*)(a + s * 64 + q * 4);
#pragma unroll
    for (int i = 0; i < 4; i++) {
      float m = av.f[i] + bv.f[i];
      sum.f[i] += m;
      sq.f[i] += m * m;
      mx.f[i] = fmaxf(mx.f[i], m);
      mn.f[i] = fminf(mn.f[i], m);
    }
  }
#pragma unroll
  for (int off = 16; off < 64; off <<= 1) {
#pragma unroll
    for (int i = 0; i < 4; i++) {
      sum.f[i] += __shfl_xor(sum.f[i], off);
      sq.f[i]  += __shfl_xor(sq.f[i], off);
      mx.f[i]  = fmaxf(mx.f[i], __shfl_xor(mx.f[i], off));
      mn.f[i]  = fminf(mn.f[i], __shfl_xor(mn.f[i], off));
    }
  }
  if (eg == 0) {
    float inv = invd[n], hn = hnb[n];
    F4 mean, stdv, mxo, mno;
#pragma unroll
    for (int i = 0; i < 4; i++) {
      mean.f[i] = sum.f[i] * inv;
      float var = sq.f[i] * inv - mean.f[i] * mean.f[i];
      stdv.f[i] = sqrtf(fmaxf(var, 0.f) + 1e-5f);
      mxo.f[i] = (hn > 0.5f) ? mx.f[i] : 0.f;
      mno.f[i] = (hn > 0.5f) ? mn.f[i] : 0.f;
    }
    *(float4*)(agg + n * 256 + q * 4) = mean.v;
    *(float4*)(agg + n * 256 + 64 + q * 4) = mxo.v;
    *(float4*)(agg + n * 256 + 128 + q * 4) = mno.v;
    *(float4*)(agg + n * 256 + 192 + q * 4) = stdv.v;
  }
}

// ---------------- posttrans + mix + graphnorm + residual (fused) ----------------
// 64 nodes/block, thread = 4 nodes x 4 channels. Three accumulator sets
// (identity/amp/att) so agg is read ONCE; scalers applied in epilogue.

__global__ __launch_bounds__(256) void k_post(
    const float* __restrict__ agg, const float* __restrict__ W, const float* __restrict__ Bv,
    const float* __restrict__ mixW, const float* __restrict__ mixB,
    const float* __restrict__ ampv, const float* __restrict__ attv,
    const float* __restrict__ snorm, float* __restrict__ x) {
  __shared__ float atile[64 * 68];  // streamed agg k-chunk, later reused as y
  __shared__ float xs[64 * 68];
  __shared__ float ampL[64], attL[64], snL[64];
  int tid = threadIdx.x;
  int n0 = blockIdx.x * 64;
#pragma unroll
  for (int s = 0; s < 4; s++) {
    int fi = tid + s * 256;
    int node = fi >> 4, jj = (fi & 15) * 4;
    int ng_g = n0 + node; if (ng_g > N_ - 1) ng_g = N_ - 1;
    *(float4*)(xs + node * 68 + jj) = *(const float4*)(x + (size_t)ng_g * 64 + jj);
  }
  if (tid < 64) {
    int n = n0 + tid; if (n > N_ - 1) n = N_ - 1;
    ampL[tid] = ampv[n];
    attL[tid] = attv[n];
    snL[tid] = snorm[n];
  }
  int cq = tid & 15, ng = tid >> 4;
  int c4 = cq * 4;
  F4 uI[4], uA[4], uT[4];
#pragma unroll
  for (int i = 0; i < 4; i++) {
    uI[i].v = make_float4(0.f, 0.f, 0.f, 0.f);
    uA[i].v = make_float4(0.f, 0.f, 0.f, 0.f);
    uT[i].v = make_float4(0.f, 0.f, 0.f, 0.f);
  }
#pragma unroll 1
  for (int c = 0; c < 4; c++) {
    __syncthreads();
#pragma unroll
    for (int s = 0; s < 4; s++) {
      int fi = tid + s * 256;
      int node = fi >> 4, jj = (fi & 15) * 4;
      int ng_g = n0 + node; if (ng_g > N_ - 1) ng_g = N_ - 1;
      *(float4*)(atile + node * 68 + jj) =
          *(const float4*)(agg + (size_t)ng_g * 256 + c * 64 + jj);
    }
    __syncthreads();
    const float* W0 = W + (size_t)(c * 64) * 64;
    const float* W1 = W + (size_t)(256 + c * 64) * 64;
    const float* W2 = W + (size_t)(512 + c * 64) * 64;
#pragma unroll 2
    for (int k = 0; k < 64; k += 4) {
      F4 av[4];
#pragma unroll
      for (int i = 0; i < 4; i++) av[i].v = *(const float4*)(atile + (ng * 4 + i) * 68 + k);
#pragma unroll
      for (int kk = 0; kk < 4; kk++) {
        F4 w0, w1, w2;
        w0.v = *(const float4*)(W0 + (k + kk) * 64 + c4);
        w1.v = *(const float4*)(W1 + (k + kk) * 64 + c4);
        w2.v = *(const float4*)(W2 + (k + kk) * 64 + c4);
#pragma unroll
        for (int i = 0; i < 4; i++) {
          float m = av[i].f[kk];
#pragma unroll
          for (int j = 0; j < 4; j++) {
            uI[i].f[j] += m * w0.f[j];
            uA[i].f[j] += m * w1.f[j];
            uT[i].f[j] += m * w2.f[j];
          }
        }
      }
    }
  }
  // x part: rows 768..831 (into identity accumulator)
  {
    const float* W3 = W + (size_t)768 * 64;
#pragma unroll 2
    for (int k = 0; k < 64; k += 4) {
      F4 av[4];
#pragma unroll
      for (int i = 0; i < 4; i++) av[i].v = *(const float4*)(xs + (ng * 4 + i) * 68 + k);
#pragma unroll
      for (int kk = 0; kk < 4; kk++) {
        F4 w; w.v = *(const float4*)(W3 + (k + kk) * 64 + c4);
#pragma unroll
        for (int i = 0; i < 4; i++) {
          float m = av[i].f[kk];
#pragma unroll
          for (int j = 0; j < 4; j++) uI[i].f[j] += m * w.f[j];
        }
      }
    }
  }
  // combine scalers + bias -> y staged into atile
  __syncthreads();
  {
    F4 bias; bias.v = *(const float4*)(Bv + c4);
#pragma unroll
    for (int i = 0; i < 4; i++) {
      float amp = ampL[ng * 4 + i], att = attL[ng * 4 + i];
      F4 y;
#pragma unroll
      for (int j = 0; j < 4; j++)
        y.f[j] = uI[i].f[j] + bias.f[j] + amp * uA[i].f[j] + att * uT[i].f[j];
      *(float4*)(atile + (ng * 4 + i) * 68 + c4) = y.v;
    }
  }
  __syncthreads();
  // mix: t = leaky_relu(y @ mixW + mixB); x = x_in + t * snorm
  F4 acc[4];
  {
    F4 mb; mb.v = *(const float4*)(mixB + c4);
#pragma unroll
    for (int i = 0; i < 4; i++) acc[i].v = mb.v;
  }
#pragma unroll 2
  for (int k = 0; k < 64; k += 4) {
    F4 av[4];
#pragma unroll
    for (int i = 0; i < 4; i++) av[i].v = *(const float4*)(atile + (ng * 4 + i) * 68 + k);
#pragma unroll
    for (int kk = 0; kk < 4; kk++) {
      F4 w; w.v = *(const float4*)(mixW + (k + kk) * 64 + c4);
#pragma unroll
      for (int i = 0; i < 4; i++) {
        float m = av[i].f[kk];
#pragma unroll
        for (int j = 0; j < 4; j++) acc[i].f[j] += m * w.f[j];
      }
    }
  }
#pragma unroll
  for (int i = 0; i < 4; i++) {
    int n = n0 + ng * 4 + i;
    if (n < N_) {
      float sn = snL[ng * 4 + i];
      F4 xv; xv.v = *(const float4*)(xs + (ng * 4 + i) * 68 + c4);
      F4 outv;
#pragma unroll
      for (int j = 0; j < 4; j++) {
        float t2 = acc[i].f[j];
        t2 = t2 > 0.f ? t2 : 0.01f * t2;
        outv.f[j] = xv.f[j] + t2 * sn;
      }
      *(float4*)(x + (size_t)n * 64 + c4) = outv.v;
    }
  }
}

// ---------------- fused readout: segmented mean (gid sorted) + MLP ----------------
// One block per graph. Binary search the node range, coalesced wave sums,
// zero atomics (replaces 1.28M-atomic k_gsum that ran 75us).

__device__ inline int lower_bound_gid(const int* __restrict__ gid, int val) {
  int lo = 0, hi = N_;
  while (lo < hi) {
    int mid = (lo + hi) >> 1;
    if (gid[mid] < val) lo = mid + 1; else hi = mid;
  }
  return lo;
}

__global__ __launch_bounds__(256) void k_readout_fused(
    const float* __restrict__ x, const int* __restrict__ gid,
    const float* __restrict__ r1W, const float* __restrict__ r1B,
    const float* __restrict__ r2W, const float* __restrict__ r2B,
    const float* __restrict__ r3W, const float* __restrict__ r3B,
    float* __restrict__ out) {
  __shared__ float part[4 * 64];
  __shared__ float hg[64];
  __shared__ float t1[32];
  __shared__ float t2[16];
  int g = blockIdx.x, tid = threadIdx.x;
  int lo = lower_bound_gid(gid, g);
  int hi = lower_bound_gid(gid, g + 1);
  int c = tid & 63, w = tid >> 6;
  float s = 0.f;
  for (int n = lo + w; n < hi; n += 4) s += x[(size_t)n * 64 + c];
  part[w * 64 + c] = s;
  __syncthreads();
  if (w == 0) {
    float tot = part[c] + part[64 + c] + part[128 + c] + part[192 + c];
    float cnt = (float)(hi - lo);
    if (cnt < 1.f) cnt = 1.f;
    hg[c] = tot / cnt;
  }
  __syncthreads();
  if (tid < 32) {
    float acc = r1B[tid];
#pragma unroll 8
    for (int k = 0; k < 64; k++) acc += hg[k] * r1W[k * 32 + tid];
    t1[tid] = fmaxf(acc, 0.f);
  }
  __syncthreads();
  if (tid < 16) {
    float acc = r2B[tid];
#pragma unroll 8
    for (int k = 0; k < 32; k++) acc += t1[k] * r2W[k * 16 + tid];
    t2[tid] = fmaxf(acc, 0.f);
  }
  __syncthreads();
  if (tid < 10) {
    float acc = r3B[tid];
#pragma unroll
    for (int k = 0; k < 16; k++) acc += t2[k] * r3W[k * 10 + tid];
    out[g * 10 + tid] = acc;
  }
}

// ---------------- launch ----------------

extern "C" void kernel_launch(void* const* d_in, const int* in_sizes, int n_in,
                              void* d_out, int out_size, void* d_ws, size_t ws_size,
                              hipStream_t stream) {
  const float* h     = (const float*)d_in[0];
  const float* snorm = (const float*)d_in[1];
  const float* embW  = (const float*)d_in[2];
  const float* embB  = (const float*)d_in[3];
  const float* preW  = (const float*)d_in[4];
  const float* preB  = (const float*)d_in[5];
  const float* postW = (const float*)d_in[6];
  const float* postB = (const float*)d_in[7];
  const float* mixW  = (const float*)d_in[8];
  const float* mixB  = (const float*)d_in[9];
  const float* r1W   = (const float*)d_in[10];
  const float* r1B   = (const float*)d_in[11];
  const float* r2W   = (const float*)d_in[12];
  const float* r2B   = (const float*)d_in[13];
  const float* r3W   = (const float*)d_in[14];
  const float* r3B   = (const float*)d_in[15];
  const int* src     = (const int*)d_in[16];
  const int* dst     = (const int*)d_in[17];
  const int* gid     = (const int*)d_in[18];
  float* out = (float*)d_out;

  char* w = (char*)d_ws;
  float* x    = (float*)w; w += (size_t)N_ * 64 * 4;
  float* av   = (float*)w; w += (size_t)N_ * 64 * 4;
  float* bv   = (float*)w; w += (size_t)N_ * 64 * 4;
  float* agg  = (float*)w; w += (size_t)N_ * 256 * 4;
  float* ampv = (float*)w; w += (size_t)N_ * 4;
  float* attv = (float*)w; w += (size_t)N_ * 4;
  float* invd = (float*)w; w += (size_t)N_ * 4;
  float* hnb  = (float*)w; w += (size_t)N_ * 4;
  int* csr    = (int*)w;   w += (size_t)E_ * 4;
  int* offs   = (int*)w;   w += (size_t)(N_ + 64) * 4;
  int* zbase  = (int*)w;
  int* deg    = (int*)w;   w += (size_t)N_ * 4;
  int* cursor = (int*)w;   w += (size_t)N_ * 4;
  int zcount = N_ + N_;

  k_zero<<<(zcount + 255) / 256, 256, 0, stream>>>(zbase, zcount);
  k_hist<<<E_ / 256, 256, 0, stream>>>(dst, deg);
  k_scan<<<1, 1024, 0, stream>>>(deg, offs, ampv, attv, invd, hnb);
  k_scatter<<<E_ / 256, 256, 0, stream>>>(src, dst, offs, cursor, csr);
  k_embed<<<N_ / 4, 256, 0, stream>>>(h, embW, embB, x);
  for (int l = 0; l < L_; l++) {
    k_pretrans<<<(N_ + 63) / 64, 256, 0, stream>>>(x, preW + l * 2 * H_ * H_, preB + l * H_, av, bv);
    k_agg<<<N_ / 4, 256, 0, stream>>>(av, bv, offs, csr, invd, hnb, agg);
    k_post<<<(N_ + 63) / 64, 256, 0, stream>>>(agg, postW + l * 13 * H_ * H_, postB + l * H_,
                                               mixW + l * H_ * H_, mixB + l * H_, ampv, attv, snorm, x);
  }
  k_readout_fused<<<G_, 256, 0, stream>>>(x, gid, r1W, r1B, r2W, r2B, r3W, r3B, out);
}